// Round 3
// baseline (590.232 us; speedup 1.0000x reference)
//
#include <hip/hip_runtime.h>

// RadarRnn1: 4-layer tanh RNN (B=512,S=1024,IN=64,H=32) + per-step FC + softmax over S.
// R11: R9/R10 measurements solve to RT=445cy/tick, barrier=280cy/iter. The tick
// chain is dominated by the own-h LDS round trip (ds_write -> lgkmcnt ->
// ds_read ~250-300cy). But h is WAVE-UNIFORM (one batch/block, one layer/wave):
// broadcast it in-register instead:
//   - pack h into 16 f16x2 words on even lanes (dpp quad_perm + cvt_pkrtz),
//     then 16x v_readlane -> SGPRs; v_dot2_f32_f16 takes the SGPR operand
//     directly (1-SGPR-per-VALU rule satisfied). Own-h chain: pack + readlane +
//     dot + tanh ~ 200cy, zero LDS.
//   - each lane computes the full 32-element dot (lanes 32-63 duplicate the
//     unit; FC's 0.5x factor already folds the 2x cascade sum).
//   - cross-layer handoff keeps the LDS double-buffer (it has a full iteration
//     of slack via the skew; latency hidden). Own-layer LDS reads are gone.
// Schedule unchanged from R10: skew-2, 2 ticks/barrier, 516 lgkmcnt-only
// barriers, FC on wave 0 via f32 h3f staging.
// u0_kernel / softmax_kernel unchanged.

#define BB 512
#define SS 1024
#define INF 64
#define HH 32
#define LL 4

typedef __fp16 v2h __attribute__((ext_vector_type(2)));

__device__ __forceinline__ v2h bch(unsigned u) { return __builtin_bit_cast(v2h, u); }
__device__ __forceinline__ unsigned bcu(v2h h) { return __builtin_bit_cast(unsigned, h); }

template <int CTRL>
__device__ __forceinline__ float dpp_add(float v) {
  int y = __builtin_amdgcn_update_dpp(0, __float_as_int(v), CTRL, 0xF, 0xF, true);
  return v + __int_as_float(y);
}
template <int CTRL>
__device__ __forceinline__ float dpp_mov(float v) {
  int y = __builtin_amdgcn_update_dpp(0, __float_as_int(v), CTRL, 0xF, 0xF, true);
  return __int_as_float(y);
}

// tanh(a) = 1 - 2/(e^{2a}+1); e^{2a} = 2^(a * 2/ln2). v_exp + v_rcp + fma.
__device__ __forceinline__ float tanh_fast(float a) {
  const float e = __builtin_amdgcn_exp2f(a * 2.885390081777927f);
  const float r = __builtin_amdgcn_rcpf(e + 1.0f);
  return __builtin_fmaf(-2.0f, r, 1.0f);
}

// full 32-element dot: 16 fdot2 in 4 independent chains (depth 4) + tree merge.
__device__ __forceinline__ float dot32(const v2h* w, const v2h* v) {
  float a = 0.f, c = 0.f, d = 0.f, e = 0.f;
#pragma unroll
  for (int j = 0; j < 4; ++j) {
    a = __builtin_amdgcn_fdot2(w[4 * j + 0], v[4 * j + 0], a, false);
    c = __builtin_amdgcn_fdot2(w[4 * j + 1], v[4 * j + 1], c, false);
    d = __builtin_amdgcn_fdot2(w[4 * j + 2], v[4 * j + 2], d, false);
    e = __builtin_amdgcn_fdot2(w[4 * j + 3], v[4 * j + 3], e, false);
  }
  return (a + c) + (d + e);
}

// lgkmcnt-only barrier: drains LDS ops (cross-wave handoff) but leaves global
// loads/stores in flight (u0 prefetch, hfin/logit stores).
#define BAR() asm volatile("s_waitcnt lgkmcnt(0)\n\ts_barrier" ::: "memory")

// ---------------- u0 = x @ W_ih0^T + (b_ih0 + b_hh0) ----------------
__global__ __launch_bounds__(256) void u0_kernel(
    const float* __restrict__ x, const float* __restrict__ W_ih0,
    const float* __restrict__ b_ih, const float* __restrict__ b_hh,
    float* __restrict__ u0) {
  __shared__ float Wl[HH * INF];  // [u][k]
  __shared__ float bl[HH];
  const int tid = threadIdx.x;
  {
    const float4* src = (const float4*)W_ih0;
    float4* dst = (float4*)Wl;
    dst[tid] = src[tid];
    dst[tid + 256] = src[tid + 256];
    if (tid < HH) bl[tid] = b_ih[tid] + b_hh[tid];
  }
  __syncthreads();

  const int row = blockIdx.x * 256 + tid;  // 2048 blocks x 256 rows
  const float4* xr = (const float4*)(x + (size_t)row * INF);
  float acc[HH];
#pragma unroll
  for (int u = 0; u < HH; ++u) acc[u] = bl[u];
#pragma unroll 4
  for (int kc = 0; kc < 16; ++kc) {
    const float4 xv = xr[kc];
#pragma unroll
    for (int u = 0; u < HH; ++u) {
      const float4 wv = ((const float4*)Wl)[u * 16 + kc];  // wave-broadcast
      acc[u] += wv.x * xv.x + wv.y * xv.y + wv.z * xv.z + wv.w * xv.w;
    }
  }
  float4* op = (float4*)(u0 + (size_t)row * HH);
#pragma unroll
  for (int j = 0; j < 8; ++j)
    op[j] = make_float4(acc[4 * j], acc[4 * j + 1], acc[4 * j + 2], acc[4 * j + 3]);
}

// ---------------- recurrent kernel: 4 waves (one per layer), 2 ticks/barrier,
// own-h broadcast via readlane/SGPR (no LDS on the serial path) ----------------
__global__ __launch_bounds__(256, 2) void rnn_kernel(
    const float* __restrict__ u0g_all, const float* __restrict__ h_state,
    const float* __restrict__ W_ih_rest, const float* __restrict__ W_hh,
    const float* __restrict__ b_ih, const float* __restrict__ b_hh,
    const float* __restrict__ fc_w, const float* __restrict__ fc_b,
    float* __restrict__ out) {
  __shared__ int hb[LL][2][2][16];  // [layer][buf=n&1][slot=t&1][pair] f16x2
  __shared__ float h3f[2][2][32];   // [buf][slot][unit]: wave3's f32 hv for FC
  __shared__ float lbuf[64];        // logit staging (wave 0)

  const int tid  = threadIdx.x;
  const int wid  = tid >> 6;   // wave id == layer id
  const int lane = tid & 63;
  const int b    = blockIdx.x; // one batch element per block
  const int u    = lane & 31;  // unit (lanes 32-63 duplicate)

  // weights: full f16-packed rows per lane (x-part of layer 0 lives in u0)
  v2h wih[16], whh[16];
  {
    const float2* ph = (const float2*)(W_hh + (size_t)(wid * HH + u) * HH);
#pragma unroll
    for (int j = 0; j < 16; ++j) whh[j] = __builtin_amdgcn_cvt_pkrtz(ph[j].x, ph[j].y);
  }
  float bias = 0.f;  // layer 0 bias folded into u0
  if (wid > 0) {
    const float2* pi =
        (const float2*)(W_ih_rest + (size_t)((wid - 1) * HH + u) * HH);
#pragma unroll
    for (int j = 0; j < 16; ++j) wih[j] = __builtin_amdgcn_cvt_pkrtz(pi[j].x, pi[j].y);
    bias = b_ih[wid * HH + u] + b_hh[wid * HH + u];
  }
  const float fcwh = fc_w[u] * 0.5f;  // units duplicated -> 64-lane sum is 2x
  const float fcb  = fc_b[0];

  // pack own hv with neighbor-unit hv (quad_perm [1,0,3,2]); even lanes hold
  // (h[2p], h[2p+1]) for p = lane>>1.
  auto packpair = [&](float hv) __attribute__((always_inline)) {
    float partner = dpp_mov<0xB1>(hv);
    return bcu(__builtin_amdgcn_cvt_pkrtz(hv, partner));
  };
  unsigned sg[16];  // wave-uniform h (16 f16x2) in SGPRs via readlane
  auto bcast16 = [&](unsigned pk) __attribute__((always_inline)) {
#pragma unroll
    for (int p = 0; p < 16; ++p) sg[p] = (unsigned)__builtin_amdgcn_readlane((int)pk, 2 * p);
  };
  auto sg2v = [&](v2h* v) __attribute__((always_inline)) {
#pragma unroll
    for (int p = 0; p < 16; ++p) v[p] = bch(sg[p]);
  };
  auto ld4 = [&](const int* p, v2h* v) __attribute__((always_inline)) {
    const uint4* q = (const uint4*)p;
    uint4 A = q[0], B = q[1], C = q[2], D = q[3];
    v[0] = bch(A.x);  v[1] = bch(A.y);  v[2] = bch(A.z);  v[3] = bch(A.w);
    v[4] = bch(B.x);  v[5] = bch(B.y);  v[6] = bch(B.z);  v[7] = bch(B.w);
    v[8] = bch(C.x);  v[9] = bch(C.y);  v[10] = bch(C.z); v[11] = bch(C.w);
    v[12] = bch(D.x); v[13] = bch(D.y); v[14] = bch(D.z); v[15] = bch(D.w);
  };
  auto store_h = [&](int l, int buf, int slot, unsigned pk) __attribute__((always_inline)) {
    if ((lane & 1) == 0 && lane < 32) hb[l][buf][slot][lane >> 1] = (int)pk;
  };
  auto fcred = [&](float v) __attribute__((always_inline)) {
    v = dpp_add<0x111>(v);  // row_shr:1
    v = dpp_add<0x112>(v);  // row_shr:2
    v = dpp_add<0x114>(v);  // row_shr:4
    v = dpp_add<0x118>(v);  // row_shr:8
    v = dpp_add<0x142>(v);  // row_bcast:15
    v = dpp_add<0x143>(v);  // row_bcast:31
    return v;               // lane 63 holds the 64-lane sum
  };

  // initial h(-1): straight into SGPRs (no LDS init; cross-layer never reads t<0)
  {
    float hv = h_state[(size_t)(wid * BB + b) * HH + u];
    bcast16(packpair(hv));
  }

  const float* ug = u0g_all + (size_t)b * SS * HH;
  float ur[8];  // rotating u0 prefetch (wave 0): 2 values/iter, distance 4 iters
  if (wid == 0) {
#pragma unroll
    for (int i = 0; i < 8; ++i) ur[i] = ug[i * HH + u];
  }
  float* const outrow = out + (size_t)b * SS;
  float* const hfin   = out + (size_t)BB * SS;

  // Schedule: wave l computes t = 2(n-l), 2(n-l)+1 at iteration n (n = 0..515).
  // Writes go to hb[l][n&1][t&1]; reads come from buf (n-1)&1 (one barrier of
  // slack). Own h flows through sg (registers), never LDS.
  if (wid == 0) {
    for (int n0 = 0; n0 < 516; n0 += 4) {
#pragma unroll
      for (int j = 0; j < 4; ++j) {
        BAR();
        const int n = n0 + j;
        const int buf = n & 1;
        if (n < 512) {  // wave-uniform
          v2h sv[16]; sg2v(sv);
          float acc0 = dot32(whh, sv) + ur[2 * j];  // u0 holds x-part + bias0
          const float hv0 = tanh_fast(acc0);
          const unsigned pk0 = packpair(hv0);
          store_h(0, buf, 0, pk0);
          bcast16(pk0);
          v2h sv1[16]; sg2v(sv1);
          float acc1 = dot32(whh, sv1) + ur[2 * j + 1];
          const float hv1 = tanh_fast(acc1);
          const unsigned pk1 = packpair(hv1);
          store_h(0, buf, 1, pk1);
          bcast16(pk1);
          if (n == 511 && lane < 32) hfin[(0 * BB + b) * HH + u] = hv1;
          int ta = 2 * n + 8; ta = ta < SS ? ta : SS - 1;
          int tb = 2 * n + 9; tb = tb < SS ? tb : SS - 1;
          ur[2 * j]     = ug[ta * HH + u];  // survives BAR (no vmcnt drain)
          ur[2 * j + 1] = ug[tb * HH + u];
        }
        if (n >= 4) {  // FC for wave3's pair from iter n-1: t = 2n-8, 2n-7
          const int tf = 2 * n - 7;
          float a0 = h3f[buf ^ 1][0][u];
          float a1 = h3f[buf ^ 1][1][u];
          float v0 = fcred(a0 * fcwh);
          float v1 = fcred(a1 * fcwh);
          if (lane == 63) {
            lbuf[(tf - 1) & 63] = v0 + fcb;
            lbuf[tf & 63]       = v1 + fcb;
          }
          if ((tf & 63) == 63) {  // coalesced flush of 64 logits
            float lv = lbuf[lane];
            outrow[tf - 63 + lane] = lv;
          }
        }
      }
    }
  } else if (wid < 3) {
    for (int n0 = 0; n0 < 516; n0 += 4) {
#pragma unroll
      for (int j = 0; j < 4; ++j) {
        BAR();
        const int n = n0 + j;
        const int buf = n & 1;
        if (n >= wid && n < 512 + wid) {  // wave-uniform
          v2h vi0[16], vi1[16];
          ld4(&hb[wid - 1][buf ^ 1][0][0], vi0);  // in h(t0), layer below
          ld4(&hb[wid - 1][buf ^ 1][1][0], vi1);  // in h(t1)
          v2h sv[16]; sg2v(sv);
          float acc0 = dot32(wih, vi0) + dot32(whh, sv) + bias;
          const float hv0 = tanh_fast(acc0);
          const unsigned pk0 = packpair(hv0);
          store_h(wid, buf, 0, pk0);
          bcast16(pk0);
          v2h sv1[16]; sg2v(sv1);
          float acc1 = dot32(wih, vi1) + dot32(whh, sv1) + bias;
          const float hv1 = tanh_fast(acc1);
          const unsigned pk1 = packpair(hv1);
          store_h(wid, buf, 1, pk1);
          bcast16(pk1);
          if (n == 511 + wid && lane < 32) hfin[(wid * BB + b) * HH + u] = hv1;
        }
      }
    }
  } else {  // wave 3: layer 3 + publish f32 hv for wave0's FC
    for (int n0 = 0; n0 < 516; n0 += 4) {
#pragma unroll
      for (int j = 0; j < 4; ++j) {
        BAR();
        const int n = n0 + j;
        const int buf = n & 1;
        if (n >= 3 && n < 515) {  // wave-uniform
          v2h vi0[16], vi1[16];
          ld4(&hb[2][buf ^ 1][0][0], vi0);
          ld4(&hb[2][buf ^ 1][1][0], vi1);
          v2h sv[16]; sg2v(sv);
          float acc0 = dot32(wih, vi0) + dot32(whh, sv) + bias;
          const float hv0 = tanh_fast(acc0);
          const unsigned pk0 = packpair(hv0);
          store_h(3, buf, 0, pk0);
          bcast16(pk0);
          if (lane < 32) h3f[buf][0][u] = hv0;  // exact f32 handoff to wave0
          v2h sv1[16]; sg2v(sv1);
          float acc1 = dot32(wih, vi1) + dot32(whh, sv1) + bias;
          const float hv1 = tanh_fast(acc1);
          const unsigned pk1 = packpair(hv1);
          store_h(3, buf, 1, pk1);
          bcast16(pk1);
          if (lane < 32) h3f[buf][1][u] = hv1;
          if (n == 514 && lane < 32) hfin[(3 * BB + b) * HH + u] = hv1;
        }
      }
    }
  }
}

__global__ __launch_bounds__(256) void softmax_kernel(float* __restrict__ out) {
  __shared__ float red[8];
  const int row = blockIdx.x;
  float* p = out + (size_t)row * SS;
  const int tid = threadIdx.x;
  float4 v = ((const float4*)p)[tid];  // 256 threads x 4 = 1024 logits
  float m = fmaxf(fmaxf(v.x, v.y), fmaxf(v.z, v.w));
#pragma unroll
  for (int d = 32; d >= 1; d >>= 1) m = fmaxf(m, __shfl_xor(m, d));
  if ((tid & 63) == 0) red[tid >> 6] = m;
  __syncthreads();
  m = fmaxf(fmaxf(red[0], red[1]), fmaxf(red[2], red[3]));
  const float e0 = __expf(v.x - m), e1 = __expf(v.y - m);
  const float e2 = __expf(v.z - m), e3 = __expf(v.w - m);
  float s = (e0 + e1) + (e2 + e3);
#pragma unroll
  for (int d = 32; d >= 1; d >>= 1) s += __shfl_xor(s, d);
  if ((tid & 63) == 0) red[4 + (tid >> 6)] = s;
  __syncthreads();
  s = (red[4] + red[5]) + (red[6] + red[7]);
  const float inv = 1.0f / s;
  float4 o;
  o.x = e0 * inv; o.y = e1 * inv; o.z = e2 * inv; o.w = e3 * inv;
  ((float4*)p)[tid] = o;
}

extern "C" void kernel_launch(void* const* d_in, const int* in_sizes, int n_in,
                              void* d_out, int out_size, void* d_ws, size_t ws_size,
                              hipStream_t stream) {
  const float* x         = (const float*)d_in[0];
  const float* h_state   = (const float*)d_in[1];
  const float* W_ih0     = (const float*)d_in[2];
  const float* W_ih_rest = (const float*)d_in[3];
  const float* W_hh      = (const float*)d_in[4];
  const float* b_ih      = (const float*)d_in[5];
  const float* b_hh      = (const float*)d_in[6];
  const float* fc_w      = (const float*)d_in[7];
  const float* fc_b      = (const float*)d_in[8];
  float* out = (float*)d_out;
  float* u0  = (float*)d_ws;  // [B,S,32] fp32 = 67 MB scratch

  hipLaunchKernelGGL(u0_kernel, dim3((BB * SS) / 256), dim3(256), 0, stream,
                     x, W_ih0, b_ih, b_hh, u0);
  hipLaunchKernelGGL(rnn_kernel, dim3(BB), dim3(256), 0, stream,
                     u0, h_state, W_ih_rest, W_hh, b_ih, b_hh, fc_w, fc_b, out);
  hipLaunchKernelGGL(softmax_kernel, dim3(BB), dim3(256), 0, stream, out);
}

// Round 4
// 456.893 us; speedup vs baseline: 1.2918x; 1.2918x over previous
//
#include <hip/hip_runtime.h>

// RadarRnn1: 4-layer tanh RNN (B=512,S=1024,IN=64,H=32) + per-step FC + softmax over S.
// R12: revert R11 (readlane/SGPR broadcast doubled fdot2 work and serialized 16
// readlanes onto the chain; 252->384us). Back to R10's ks-split structure
// (B=280cy/iter, RT=445cy/tick), now hiding the post-barrier LDS reads:
//   - layer skew = 2 barriers (wave l computes pair p = n-2l at iter n; uses
//     producer's pair p written at iter n-2, visible since BAR(n-1)). The
//     consumer ISSUES the ds_read during iter n-1 (ping-pong reg sets, j&1
//     compile-time under unroll-4), so inputs are in registers at BAR(n):
//     the ~150cy post-barrier read leaves the chain. Double-buffer is still
//     safe: the read drains at the consumer's own lgkmcnt(0) one barrier
//     before the producer rewrites that buffer.
//   - own-h carry for next iter: write slot1 then immediately read it back
//     (in-wave LDS is in-order); its latency lands in the pre-BAR drain where
//     all waves are waiting anyway.
//   - only exposed LDS latency left: the true in-iteration slot0->slot1
//     own-h roundtrip, partially hidden behind slot1's independent wih dot.
// Arithmetic identical to R10 (same fdot2/dpp/tanh/FC ops) -> same absmax.
// u0_kernel / softmax_kernel unchanged.

#define BB 512
#define SS 1024
#define INF 64
#define HH 32
#define LL 4

typedef __fp16 v2h __attribute__((ext_vector_type(2)));

__device__ __forceinline__ v2h bch(unsigned u) { return __builtin_bit_cast(v2h, u); }
__device__ __forceinline__ unsigned bcu(v2h h) { return __builtin_bit_cast(unsigned, h); }

template <int CTRL>
__device__ __forceinline__ float dpp_add(float v) {
  int y = __builtin_amdgcn_update_dpp(0, __float_as_int(v), CTRL, 0xF, 0xF, true);
  return v + __int_as_float(y);
}
template <int CTRL>
__device__ __forceinline__ float dpp_mov(float v) {
  int y = __builtin_amdgcn_update_dpp(0, __float_as_int(v), CTRL, 0xF, 0xF, true);
  return __int_as_float(y);
}

// tanh(a) = 1 - 2/(e^{2a}+1); e^{2a} = 2^(a * 2/ln2). v_exp + v_rcp + fma.
__device__ __forceinline__ float tanh_fast(float a) {
  const float e = __builtin_amdgcn_exp2f(a * 2.885390081777927f);
  const float r = __builtin_amdgcn_rcpf(e + 1.0f);
  return __builtin_fmaf(-2.0f, r, 1.0f);
}

// 16-half dot (ks-half): 8 fdot2 in 2 chains of depth 4.
__device__ __forceinline__ float dot16p(const v2h* w, const v2h* v) {
  float a = 0.f, c = 0.f;
#pragma unroll
  for (int j = 0; j < 4; ++j) {
    a = __builtin_amdgcn_fdot2(w[2 * j + 0], v[2 * j + 0], a, false);
    c = __builtin_amdgcn_fdot2(w[2 * j + 1], v[2 * j + 1], c, false);
  }
  return a + c;
}

// lgkmcnt-only barrier: drains LDS ops (cross-wave handoff) but leaves global
// loads/stores in flight (u0 prefetch, hfin/logit stores).
#define BAR() asm volatile("s_waitcnt lgkmcnt(0)\n\ts_barrier" ::: "memory")

// ---------------- u0 = x @ W_ih0^T + (b_ih0 + b_hh0) ----------------
__global__ __launch_bounds__(256) void u0_kernel(
    const float* __restrict__ x, const float* __restrict__ W_ih0,
    const float* __restrict__ b_ih, const float* __restrict__ b_hh,
    float* __restrict__ u0) {
  __shared__ float Wl[HH * INF];  // [u][k]
  __shared__ float bl[HH];
  const int tid = threadIdx.x;
  {
    const float4* src = (const float4*)W_ih0;
    float4* dst = (float4*)Wl;
    dst[tid] = src[tid];
    dst[tid + 256] = src[tid + 256];
    if (tid < HH) bl[tid] = b_ih[tid] + b_hh[tid];
  }
  __syncthreads();

  const int row = blockIdx.x * 256 + tid;  // 2048 blocks x 256 rows
  const float4* xr = (const float4*)(x + (size_t)row * INF);
  float acc[HH];
#pragma unroll
  for (int u = 0; u < HH; ++u) acc[u] = bl[u];
#pragma unroll 4
  for (int kc = 0; kc < 16; ++kc) {
    const float4 xv = xr[kc];
#pragma unroll
    for (int u = 0; u < HH; ++u) {
      const float4 wv = ((const float4*)Wl)[u * 16 + kc];  // wave-broadcast
      acc[u] += wv.x * xv.x + wv.y * xv.y + wv.z * xv.z + wv.w * xv.w;
    }
  }
  float4* op = (float4*)(u0 + (size_t)row * HH);
#pragma unroll
  for (int j = 0; j < 8; ++j)
    op[j] = make_float4(acc[4 * j], acc[4 * j + 1], acc[4 * j + 2], acc[4 * j + 3]);
}

// ---------------- recurrent kernel: 4 waves (one per layer), skew-2 barriers,
// prefetched LDS inputs (reads issued one iteration ahead) ----------------
__global__ __launch_bounds__(256, 2) void rnn_kernel(
    const float* __restrict__ u0g_all, const float* __restrict__ h_state,
    const float* __restrict__ W_ih_rest, const float* __restrict__ W_hh,
    const float* __restrict__ b_ih, const float* __restrict__ b_hh,
    const float* __restrict__ fc_w, const float* __restrict__ fc_b,
    float* __restrict__ out) {
  __shared__ int hb[LL][2][2][16];  // [layer][buf=n&1][slot=t&1][pair] f16x2
  __shared__ float h3f[2][2][32];   // [buf][slot][unit]: wave3's f32 hv for FC
  __shared__ float lbuf[64];        // logit staging (wave 0)

  const int tid  = threadIdx.x;
  const int wid  = tid >> 6;   // wave id == layer id
  const int lane = tid & 63;
  const int b    = blockIdx.x; // one batch element per block
  const int ks   = lane & 1;   // k-split half
  const int h    = lane >> 1;  // output unit 0..31

  // weights: f16-packed h-matrices only (x-part of layer 0 lives in u0)
  v2h wih[8], whh[8];
  {
    const float2* ph = (const float2*)(W_hh + (size_t)(wid * HH + h) * HH + ks * 16);
#pragma unroll
    for (int j = 0; j < 8; ++j) whh[j] = __builtin_amdgcn_cvt_pkrtz(ph[j].x, ph[j].y);
  }
  float bias = 0.f;  // layer 0 bias folded into u0
  if (wid > 0) {
    const float2* pi =
        (const float2*)(W_ih_rest + (size_t)((wid - 1) * HH + h) * HH + ks * 16);
#pragma unroll
    for (int j = 0; j < 8; ++j) wih[j] = __builtin_amdgcn_cvt_pkrtz(pi[j].x, pi[j].y);
    bias = b_ih[wid * HH + h] + b_hh[wid * HH + h];
  }
  const float fcwh = fc_w[h] * 0.5f;  // both ks lanes hold hv -> 64-lane sum is 2x
  const float fcb  = fc_b[0];

  // own h(-1) straight into registers (packed ks-half), no LDS init needed
  v2h sv[8];
  {
    const float2* hs = (const float2*)(h_state + (size_t)(wid * BB + b) * HH);
#pragma unroll
    for (int j = 0; j < 8; ++j)
      sv[j] = __builtin_amdgcn_cvt_pkrtz(hs[ks * 8 + j].x, hs[ks * 8 + j].y);
  }

  const float* ug = u0g_all + (size_t)b * SS * HH;
  float ur[8];  // rotating u0 prefetch (wave 0): 2 values/iter, 4 iters ahead
  if (wid == 0) {
#pragma unroll
    for (int i = 0; i < 8; ++i) ur[i] = ug[i * HH + h];
  }
  float* const outrow = out + (size_t)b * SS;
  float* const hfin   = out + (size_t)BB * SS;

  auto ld8 = [&](const int* p, v2h* v) __attribute__((always_inline)) {
    const uint4* q = (const uint4*)p;
    uint4 A = q[0], B = q[1];
    v[0] = bch(A.x); v[1] = bch(A.y); v[2] = bch(A.z); v[3] = bch(A.w);
    v[4] = bch(B.x); v[5] = bch(B.y); v[6] = bch(B.z); v[7] = bch(B.w);
  };
  // pack own hv with neighbor-unit hv (quad_perm [2,3,2,3]) and store by 16 lanes
  auto store_h = [&](int l, int buf, int slot, float hv) __attribute__((always_inline)) {
    float partner = dpp_mov<0xEE>(hv);
    if ((lane & 3) == 0)
      hb[l][buf][slot][lane >> 2] = (int)bcu(__builtin_amdgcn_cvt_pkrtz(hv, partner));
  };
  auto fcred = [&](float v) __attribute__((always_inline)) {
    v = dpp_add<0x111>(v);  // row_shr:1
    v = dpp_add<0x112>(v);  // row_shr:2
    v = dpp_add<0x114>(v);  // row_shr:4
    v = dpp_add<0x118>(v);  // row_shr:8
    v = dpp_add<0x142>(v);  // row_bcast:15
    v = dpp_add<0x143>(v);  // row_bcast:31
    return v;               // lane 63 holds the 64-lane sum
  };

  // Schedule: wave l computes pair p = n - 2l (t = 2p, 2p+1) at iteration n.
  // hb write buffer = n&1. Consumer input (producer pair p, written at n-2,
  // buf (n-2)&1 = n&1) is ds_read-issued at iter n-1 into vi[(n)&1] and is in
  // registers at BAR(n). No initial __syncthreads: nothing reads hb before its
  // producer's write+BAR. All waves run n = 0..519 (520 barriers each).
  v2h vi[2][2][8];  // [iter parity][slot][word] - indices compile-time (j&1)

  if (wid == 0) {
    for (int n0 = 0; n0 < 520; n0 += 4) {
#pragma unroll
      for (int j = 0; j < 4; ++j) {
        BAR();
        const int n = n0 + j;
        const int buf = j & 1;  // == n&1 (n0 % 4 == 0)
        // FC loads for this iter (wave3's pair from iter n-1), issued early
        float a0 = 0.f, a1 = 0.f;
        const bool fc_on = (n >= 7 && n <= 518);
        if (fc_on) {
          a0 = h3f[buf ^ 1][0][h];
          a1 = h3f[buf ^ 1][1][h];
        }
        if (n <= 511) {  // wave-uniform
          // slot0: own h(2n-1) already in regs (sv)
          float acc0 = dot16p(whh, sv);
          acc0 = dpp_add<0xB1>(acc0) + ur[2 * j];  // u0 holds x-part + bias0
          const float hv0 = tanh_fast(acc0);
          store_h(0, buf, 0, hv0);
          v2h sv0[8];
          ld8(&hb[0][buf][0][ks * 8], sv0);  // in-wave roundtrip (exposed)
          float acc1 = dot16p(whh, sv0);
          acc1 = dpp_add<0xB1>(acc1) + ur[2 * j + 1];
          const float hv1 = tanh_fast(acc1);
          store_h(0, buf, 1, hv1);
          ld8(&hb[0][buf][1][ks * 8], sv);   // own-h carry; drains at next BAR
          if (n == 511 && ks == 0) hfin[(0 * BB + b) * HH + h] = hv1;
          int ta = 2 * n + 8; ta = ta < SS ? ta : SS - 1;
          int tb = 2 * n + 9; tb = tb < SS ? tb : SS - 1;
          ur[2 * j]     = ug[ta * HH + h];  // global; survives BAR (lgkm-only)
          ur[2 * j + 1] = ug[tb * HH + h];
        }
        if (fc_on) {  // FC for t = 2n-14, 2n-13
          const int tf = 2 * n - 13;
          float v0 = fcred(a0 * fcwh);
          float v1 = fcred(a1 * fcwh);
          if (lane == 63) {
            lbuf[(tf - 1) & 63] = v0 + fcb;
            lbuf[tf & 63]       = v1 + fcb;
          }
          if ((tf & 63) == 63) {  // coalesced flush of 64 logits
            float lv = lbuf[lane];
            outrow[tf - 63 + lane] = lv;
          }
        }
      }
    }
  } else if (wid < 3) {
    const int lo = 2 * wid, hi = 511 + 2 * wid;
    for (int n0 = 0; n0 < 520; n0 += 4) {
#pragma unroll
      for (int j = 0; j < 4; ++j) {
        BAR();
        const int n = n0 + j;
        const int buf = j & 1;  // == n&1
        // prefetch input for iter n+1 (producer pair p+1, written at n-1,
        // buf (n-1)&1 = buf^1) -> vi[buf^1]
        if (n >= lo - 1 && n <= hi - 1) {
          ld8(&hb[wid - 1][buf ^ 1][0][ks * 8], vi[buf ^ 1][0]);
          ld8(&hb[wid - 1][buf ^ 1][1][ks * 8], vi[buf ^ 1][1]);
        }
        if (n >= lo && n <= hi) {  // wave-uniform
          float acc0 = dot16p(wih, vi[buf][0]) + dot16p(whh, sv);
          acc0 = dpp_add<0xB1>(acc0) + bias;
          const float hv0 = tanh_fast(acc0);
          store_h(wid, buf, 0, hv0);
          v2h sv0[8];
          ld8(&hb[wid][buf][0][ks * 8], sv0);       // in-iter roundtrip
          float acc1 = dot16p(wih, vi[buf][1]);     // independent: overlaps wait
          acc1 += dot16p(whh, sv0);
          acc1 = dpp_add<0xB1>(acc1) + bias;
          const float hv1 = tanh_fast(acc1);
          store_h(wid, buf, 1, hv1);
          ld8(&hb[wid][buf][1][ks * 8], sv);        // own-h carry
          if (n == hi && ks == 0) hfin[(wid * BB + b) * HH + h] = hv1;
        }
      }
    }
  } else {  // wave 3: layer 3 + publish f32 hv for wave0's FC
    for (int n0 = 0; n0 < 520; n0 += 4) {
#pragma unroll
      for (int j = 0; j < 4; ++j) {
        BAR();
        const int n = n0 + j;
        const int buf = j & 1;  // == n&1
        if (n >= 5 && n <= 516) {
          ld8(&hb[2][buf ^ 1][0][ks * 8], vi[buf ^ 1][0]);
          ld8(&hb[2][buf ^ 1][1][ks * 8], vi[buf ^ 1][1]);
        }
        if (n >= 6 && n <= 517) {  // wave-uniform
          float acc0 = dot16p(wih, vi[buf][0]) + dot16p(whh, sv);
          acc0 = dpp_add<0xB1>(acc0) + bias;
          const float hv0 = tanh_fast(acc0);
          store_h(3, buf, 0, hv0);
          if (ks == 0) h3f[buf][0][h] = hv0;  // exact f32 handoff to wave0
          v2h sv0[8];
          ld8(&hb[3][buf][0][ks * 8], sv0);
          float acc1 = dot16p(wih, vi[buf][1]);
          acc1 += dot16p(whh, sv0);
          acc1 = dpp_add<0xB1>(acc1) + bias;
          const float hv1 = tanh_fast(acc1);
          store_h(3, buf, 1, hv1);
          if (ks == 0) h3f[buf][1][h] = hv1;
          ld8(&hb[3][buf][1][ks * 8], sv);
          if (n == 517 && ks == 0) hfin[(3 * BB + b) * HH + h] = hv1;
        }
      }
    }
  }
}

__global__ __launch_bounds__(256) void softmax_kernel(float* __restrict__ out) {
  __shared__ float red[8];
  const int row = blockIdx.x;
  float* p = out + (size_t)row * SS;
  const int tid = threadIdx.x;
  float4 v = ((const float4*)p)[tid];  // 256 threads x 4 = 1024 logits
  float m = fmaxf(fmaxf(v.x, v.y), fmaxf(v.z, v.w));
#pragma unroll
  for (int d = 32; d >= 1; d >>= 1) m = fmaxf(m, __shfl_xor(m, d));
  if ((tid & 63) == 0) red[tid >> 6] = m;
  __syncthreads();
  m = fmaxf(fmaxf(red[0], red[1]), fmaxf(red[2], red[3]));
  const float e0 = __expf(v.x - m), e1 = __expf(v.y - m);
  const float e2 = __expf(v.z - m), e3 = __expf(v.w - m);
  float s = (e0 + e1) + (e2 + e3);
#pragma unroll
  for (int d = 32; d >= 1; d >>= 1) s += __shfl_xor(s, d);
  if ((tid & 63) == 0) red[4 + (tid >> 6)] = s;
  __syncthreads();
  s = (red[4] + red[5]) + (red[6] + red[7]);
  const float inv = 1.0f / s;
  float4 o;
  o.x = e0 * inv; o.y = e1 * inv; o.z = e2 * inv; o.w = e3 * inv;
  ((float4*)p)[tid] = o;
}

extern "C" void kernel_launch(void* const* d_in, const int* in_sizes, int n_in,
                              void* d_out, int out_size, void* d_ws, size_t ws_size,
                              hipStream_t stream) {
  const float* x         = (const float*)d_in[0];
  const float* h_state   = (const float*)d_in[1];
  const float* W_ih0     = (const float*)d_in[2];
  const float* W_ih_rest = (const float*)d_in[3];
  const float* W_hh      = (const float*)d_in[4];
  const float* b_ih      = (const float*)d_in[5];
  const float* b_hh      = (const float*)d_in[6];
  const float* fc_w      = (const float*)d_in[7];
  const float* fc_b      = (const float*)d_in[8];
  float* out = (float*)d_out;
  float* u0  = (float*)d_ws;  // [B,S,32] fp32 = 67 MB scratch

  hipLaunchKernelGGL(u0_kernel, dim3((BB * SS) / 256), dim3(256), 0, stream,
                     x, W_ih0, b_ih, b_hh, u0);
  hipLaunchKernelGGL(rnn_kernel, dim3(BB), dim3(256), 0, stream,
                     u0, h_state, W_ih_rest, W_hh, b_ih, b_hh, fc_w, fc_b, out);
  hipLaunchKernelGGL(softmax_kernel, dim3(BB), dim3(256), 0, stream, out);
}